// Round 2
// baseline (1453.188 us; speedup 1.0000x reference)
//
#include <hip/hip_runtime.h>

typedef unsigned short u16;
typedef unsigned int u32;

#define HEADS 8
#define DIM 512
#define HH 96
#define WW 96
#define NPIX (HH*WW)      // 9216
#define M_TOT (4*NPIX)    // 36864
#define SCALE 0.125f

__device__ __forceinline__ float b2f(u16 v){
    union{float f;u32 u;}x; x.u=((u32)v)<<16; return x.f;
}
__device__ __forceinline__ float blo(u32 v){
    union{float f;u32 u;}x; x.u=v<<16; return x.f;
}
__device__ __forceinline__ float bhi(u32 v){
    union{float f;u32 u;}x; x.u=v&0xffff0000u; return x.f;
}
__device__ __forceinline__ u16 f2b(float f){
    union{float f;u32 u;}x; x.f=f;
    u32 u=x.u + 0x7fffu + ((x.u>>16)&1u);
    return (u16)(u>>16);
}
__device__ __forceinline__ u32 pack2(float a,float b){
    return (u32)f2b(a) | ((u32)f2b(b)<<16);
}

// ---------------------------------------------------------------------------
// Dtype detector: if w_qkv is bf16, even-indexed u16s are valid bf16 with
// exponent near 122 (values ~N(0, 1/512)); if fp32, even u16s are float low
// halves = uniform random bits (exp-in-range rate ~11%). flag=1 -> bf16.
// ---------------------------------------------------------------------------
__global__ void detect_dtype(const u16* __restrict__ wq, int* __restrict__ flag){
    __shared__ int cnt;
    if (threadIdx.x==0) cnt=0;
    __syncthreads();
    u16 u = wq[2*threadIdx.x];
    int e = (u>>7)&0xff;
    if (e>=100 && e<=128) atomicAdd(&cnt,1);
    __syncthreads();
    if (threadIdx.x==0) *flag = (cnt>128)?1:0;
}

// ---------------------------------------------------------------------------
// Kernel 1: QKV projection. C[m,n] = sum_k A[m,k]*W[n,k]
//   A[m,k] = x[b,k,h,w]  (m = b*9216 + h*96 + w; k-stride = 9216)
//   W = w_qkv [1536, 512] row-major (k contiguous)
//   Output qkv_ws[m*1536 + n]  (pixel-major, bf16)
// ---------------------------------------------------------------------------
__global__ __launch_bounds__(256)
void qkv_gemm(const void* __restrict__ xv, const void* __restrict__ wv,
              const int* __restrict__ flag, u16* __restrict__ qkv){
    __shared__ __align__(16) float As[16][68];
    __shared__ __align__(16) float Bs[16][68];
    const int isb = *flag;
    const u16*   x16 = (const u16*)xv;
    const float* x32 = (const float*)xv;
    const u16*   w16 = (const u16*)wv;
    const float* w32 = (const float*)wv;
    const int t  = threadIdx.x;
    const int bx = blockIdx.x;      // 24 n-tiles
    const int by = blockIdx.y;      // 576 m-tiles
    const int tx = t & 15, ty = t >> 4;
    const int m0 = by*64;
    const int bat  = m0 / NPIX;     // 9216 % 64 == 0: uniform per block
    const int pix0 = m0 - bat*NPIX;
    const int am  = t & 63;
    const int ak0 = t >> 6;         // 0..3
    const int bk  = t & 15;
    const int bn0 = t >> 4;         // 0..15
    const size_t xoff = (size_t)bat*DIM*NPIX + pix0 + am;
    float acc[4][4] = {{0.f}};
    for (int kt = 0; kt < DIM; kt += 16){
        #pragma unroll
        for (int i=0;i<4;i++){
            int kl = ak0 + i*4;
            size_t idx = xoff + (size_t)(kt+kl)*NPIX;
            As[kl][am] = isb ? b2f(x16[idx]) : x32[idx];
        }
        #pragma unroll
        for (int i=0;i<4;i++){
            int nl = bn0 + i*16;
            size_t idx = (size_t)(bx*64+nl)*DIM + kt + bk;
            Bs[bk][nl] = isb ? b2f(w16[idx]) : w32[idx];
        }
        __syncthreads();
        #pragma unroll
        for (int k=0;k<16;k++){
            float4 a4 = *reinterpret_cast<const float4*>(&As[k][ty*4]);
            float4 b4 = *reinterpret_cast<const float4*>(&Bs[k][tx*4]);
            float a[4] = {a4.x,a4.y,a4.z,a4.w};
            float b[4] = {b4.x,b4.y,b4.z,b4.w};
            #pragma unroll
            for(int p=0;p<4;p++)
                #pragma unroll
                for(int q=0;q<4;q++) acc[p][q] += a[p]*b[q];
        }
        __syncthreads();
    }
    u32* q32 = (u32*)qkv;
    #pragma unroll
    for(int p=0;p<4;p++){
        size_t rowoff = (size_t)(m0 + ty*4 + p)*(3*DIM) + (size_t)bx*64 + tx*4;
        q32[(rowoff>>1)]   = pack2(acc[p][0], acc[p][1]);
        q32[(rowoff>>1)+1] = pack2(acc[p][2], acc[p][3]);
    }
}

// ---------------------------------------------------------------------------
// Kernel 2: width-axis attention. One block per (b, head, row). 256 threads.
// qkv_ws (bf16 internal) -> attn_ws (bf16 internal, [pixel*512 + head*64+d]).
// ---------------------------------------------------------------------------
__global__ __launch_bounds__(256)
void attn_kernel(const u16* __restrict__ qkv, u16* __restrict__ attno){
    __shared__ u32 Qs[96][33];      // Q, then V (reused)
    __shared__ u32 Ks[96][33];
    __shared__ float Ss[96][97];
    const int t   = threadIdx.x;
    const int blk = blockIdx.x;     // 3072
    const int row  = blk % HH;
    const int bh   = blk / HH;
    const int head = bh & 7;
    const int bat  = bh >> 3;
    const u32* qkv32 = (const u32*)qkv;
    const size_t pixrow = (size_t)(bat*NPIX + row*WW);
    const size_t base2  = pixrow*768 + (size_t)head*32;
    const int dd = t & 31;
    const int j0 = t >> 5;
    for (int j=j0;j<WW;j+=8){
        Qs[j][dd] = qkv32[base2 +       (size_t)j*768 + dd];
        Ks[j][dd] = qkv32[base2 + 256 + (size_t)j*768 + dd];
    }
    __syncthreads();
    const int tx = t & 15, ty = t >> 4;
    {   // S = scale * Q K^T
        float acc[6][6] = {{0.f}};
        for (int d2=0; d2<32; d2++){
            float ql[6], qh[6], kl[6], kh[6];
            #pragma unroll
            for (int a=0;a<6;a++){ u32 u = Qs[ty*6+a][d2]; ql[a]=blo(u); qh[a]=bhi(u); }
            #pragma unroll
            for (int c=0;c<6;c++){ u32 u = Ks[tx*6+c][d2]; kl[c]=blo(u); kh[c]=bhi(u); }
            #pragma unroll
            for (int a=0;a<6;a++)
                #pragma unroll
                for (int c=0;c<6;c++) acc[a][c] += ql[a]*kl[c] + qh[a]*kh[c];
        }
        #pragma unroll
        for (int a=0;a<6;a++)
            #pragma unroll
            for (int c=0;c<6;c++) Ss[ty*6+a][tx*6+c] = acc[a][c]*SCALE;
    }
    __syncthreads();
    for (int j=j0;j<WW;j+=8){
        Qs[j][dd] = qkv32[base2 + 512 + (size_t)j*768 + dd];  // V
    }
    if (t < HH){
        float m = -1e30f;
        for (int j=0;j<WW;j++) m = fmaxf(m, Ss[t][j]);
        float s = 0.f;
        for (int j=0;j<WW;j++){ float e = __expf(Ss[t][j]-m); Ss[t][j]=e; s+=e; }
        float r = 1.f/s;
        for (int j=0;j<WW;j++) Ss[t][j] *= r;
    }
    __syncthreads();
    {   // O = P V
        float acc[6][4] = {{0.f}};
        for (int j=0;j<WW;j++){
            u32 u0 = Qs[j][tx*2], u1 = Qs[j][tx*2+1];
            float v0=blo(u0), v1=bhi(u0), v2=blo(u1), v3=bhi(u1);
            #pragma unroll
            for (int a=0;a<6;a++){
                float p = Ss[ty*6+a][j];
                acc[a][0]+=p*v0; acc[a][1]+=p*v1; acc[a][2]+=p*v2; acc[a][3]+=p*v3;
            }
        }
        u32* o32 = (u32*)attno;
        #pragma unroll
        for (int a=0;a<6;a++){
            size_t pix = pixrow + (size_t)(ty*6 + a);
            size_t ob  = pix*256 + (size_t)head*32 + tx*2;
            o32[ob]   = pack2(acc[a][0], acc[a][1]);
            o32[ob+1] = pack2(acc[a][2], acc[a][3]);
        }
    }
}

// ---------------------------------------------------------------------------
// Kernel 3: output projection + bias. Output dtype follows detected flag.
// ---------------------------------------------------------------------------
__global__ __launch_bounds__(256)
void out_gemm(const u16* __restrict__ a_in, const void* __restrict__ wv,
              const void* __restrict__ bv, const int* __restrict__ flag,
              void* __restrict__ outv){
    __shared__ __align__(16) float As[16][68];
    __shared__ __align__(16) float Bs[16][68];
    const int isb = *flag;
    const u16*   w16 = (const u16*)wv;
    const float* w32 = (const float*)wv;
    const u16*   b16 = (const u16*)bv;
    const float* b32 = (const float*)bv;
    const int t  = threadIdx.x;
    const int bx = blockIdx.x;   // 8
    const int by = blockIdx.y;   // 576
    const int tx = t & 15, ty = t >> 4;
    const int m0 = by*64;
    const int kq = t & 15;
    const int r0 = t >> 4;
    float acc[4][4] = {{0.f}};
    for (int kt=0; kt<DIM; kt+=16){
        #pragma unroll
        for (int i=0;i<4;i++){
            int ml = r0 + i*16;
            As[kq][ml] = b2f(a_in[(size_t)(m0+ml)*DIM + kt + kq]);
        }
        #pragma unroll
        for (int i=0;i<4;i++){
            int nl = r0 + i*16;
            size_t idx = (size_t)(bx*64+nl)*DIM + kt + kq;
            Bs[kq][nl] = isb ? b2f(w16[idx]) : w32[idx];
        }
        __syncthreads();
        #pragma unroll
        for (int k=0;k<16;k++){
            float4 a4 = *reinterpret_cast<const float4*>(&As[k][ty*4]);
            float4 b4 = *reinterpret_cast<const float4*>(&Bs[k][tx*4]);
            float a[4] = {a4.x,a4.y,a4.z,a4.w};
            float b[4] = {b4.x,b4.y,b4.z,b4.w};
            #pragma unroll
            for(int p=0;p<4;p++)
                #pragma unroll
                for(int q=0;q<4;q++) acc[p][q] += a[p]*b[q];
        }
        __syncthreads();
    }
    const int bat  = m0 / NPIX;
    const int pix0 = m0 - bat*NPIX;
    if (isb){
        u32* o32 = (u32*)outv;
        #pragma unroll
        for(int q=0;q<4;q++){
            int n = bx*64 + tx*4 + q;
            float bias = b2f(b16[n]);
            size_t off = (size_t)(bat*DIM + n)*NPIX + pix0 + ty*4;
            o32[(off>>1)]   = pack2(acc[0][q]+bias, acc[1][q]+bias);
            o32[(off>>1)+1] = pack2(acc[2][q]+bias, acc[3][q]+bias);
        }
    } else {
        float* of = (float*)outv;
        #pragma unroll
        for(int q=0;q<4;q++){
            int n = bx*64 + tx*4 + q;
            float bias = b32[n];
            size_t off = (size_t)(bat*DIM + n)*NPIX + pix0 + ty*4;
            float4 st;
            st.x = acc[0][q]+bias; st.y = acc[1][q]+bias;
            st.z = acc[2][q]+bias; st.w = acc[3][q]+bias;
            *reinterpret_cast<float4*>(of + off) = st;
        }
    }
}

extern "C" void kernel_launch(void* const* d_in, const int* in_sizes, int n_in,
                              void* d_out, int out_size, void* d_ws, size_t ws_size,
                              hipStream_t stream){
    const void* x    = d_in[0];
    const void* wqkv = d_in[1];
    const void* wout = d_in[2];
    const void* bout = d_in[3];
    int* flag    = (int*)d_ws;
    u16* qkv_ws  = (u16*)((char*)d_ws + 256);            // [36864,1536] bf16
    u16* attn_ws = qkv_ws + (size_t)M_TOT*3*DIM;         // [36864,512]  bf16
    detect_dtype<<<1, 256, 0, stream>>>((const u16*)wqkv, flag);
    dim3 g1(24, 576);
    dim3 g3(8, 576);
    qkv_gemm<<<g1, 256, 0, stream>>>(x, wqkv, flag, qkv_ws);
    attn_kernel<<<3072, 256, 0, stream>>>(qkv_ws, attn_ws);
    out_gemm<<<g3, 256, 0, stream>>>(attn_ws, wout, bout, flag, d_out);
}

// Round 3
// 477.847 us; speedup vs baseline: 3.0411x; 3.0411x over previous
//
#include <hip/hip_runtime.h>

typedef unsigned short u16;
typedef unsigned int u32;
typedef __attribute__((ext_vector_type(8))) short short8;
typedef __attribute__((ext_vector_type(4))) float floatx4;

#define HEADS 8
#define DIM 512          // K for both GEMMs
#define HH 96
#define WW 96
#define NPIX 9216
#define M_TOT 36864
#define N_QKV 1536
#define SCALE 0.125f

__device__ __forceinline__ float b2f(u16 v){
    union{float f;u32 u;}x; x.u=((u32)v)<<16; return x.f;
}
__device__ __forceinline__ float blo(u32 v){
    union{float f;u32 u;}x; x.u=v<<16; return x.f;
}
__device__ __forceinline__ float bhi(u32 v){
    union{float f;u32 u;}x; x.u=v&0xffff0000u; return x.f;
}
__device__ __forceinline__ u16 f2b(float f){
    union{float f;u32 u;}x; x.f=f;
    u32 u=x.u + 0x7fffu + ((x.u>>16)&1u);
    return (u16)(u>>16);
}
__device__ __forceinline__ u32 pack2(float a,float b){
    return (u32)f2b(a) | ((u32)f2b(b)<<16);
}

// async global->LDS, 16 B per lane; lds dest = wave-uniform base + lane*16
__device__ __forceinline__ void gload16(const u16* g, u16* l){
    __builtin_amdgcn_global_load_lds(
        (const __attribute__((address_space(1))) u32*)g,
        (__attribute__((address_space(3))) u32*)l, 16, 0, 0);
}

// ---------------------------------------------------------------------------
// dtype detector (bf16 vs fp32 inputs), as validated in round 2
// ---------------------------------------------------------------------------
__global__ void detect_dtype(const u16* __restrict__ wq, int* __restrict__ flag){
    __shared__ int cnt;
    if (threadIdx.x==0) cnt=0;
    __syncthreads();
    u16 u = wq[2*threadIdx.x];
    int e = (u>>7)&0xff;
    if (e>=100 && e<=128) atomicAdd(&cnt,1);
    __syncthreads();
    if (threadIdx.x==0) *flag = (cnt>128)?1:0;
}

// ---------------------------------------------------------------------------
// Weights -> bf16 (layout unchanged, [n][k] k-contiguous)
// ---------------------------------------------------------------------------
__global__ __launch_bounds__(256)
void convert_w(const void* __restrict__ wq, const void* __restrict__ wo,
               const int* __restrict__ flag, u16* __restrict__ wqb, u16* __restrict__ wob){
    const int isb = *flag;
    int i = blockIdx.x*256 + threadIdx.x;
    const int nq = N_QKV*DIM;                 // 786432
    if (i < nq){
        wqb[i] = isb ? ((const u16*)wq)[i] : f2b(((const float*)wq)[i]);
    } else {
        int j = i - nq;                       // < 262144
        wob[j] = isb ? ((const u16*)wo)[j] : f2b(((const float*)wo)[j]);
    }
}

// ---------------------------------------------------------------------------
// x [b][c][pix] (fp32 or bf16) -> xb [b*9216+pix][c] bf16   (transpose)
// ---------------------------------------------------------------------------
__global__ __launch_bounds__(256)
void convert_x(const void* __restrict__ xv, const int* __restrict__ flag,
               u16* __restrict__ xb){
    __shared__ u16 tile[64][65];
    const int isb = *flag;
    const int p0 = blockIdx.x*64, c0 = blockIdx.y*64, b = blockIdx.z;
    const int t = threadIdx.x;
    const int pl = t&63, c4 = t>>6;
    const float* x32 = (const float*)xv;
    const u16*   x16 = (const u16*)xv;
    size_t src = ((size_t)b*DIM + c0 + c4)*NPIX + p0 + pl;
    #pragma unroll
    for (int i=0;i<16;i++){
        int cl = c4 + i*4;
        size_t s = src + (size_t)i*4*NPIX;
        tile[cl][pl] = isb ? x16[s] : f2b(x32[s]);
    }
    __syncthreads();
    const int cu = t&31, r8 = t>>5;
    u32* xb32 = (u32*)xb;
    #pragma unroll
    for (int i=0;i<8;i++){
        int pr = r8 + i*8;
        u32 v = (u32)tile[2*cu][pr] | ((u32)tile[2*cu+1][pr]<<16);
        xb32[((size_t)b*NPIX + p0 + pr)*(DIM/2) + (c0>>1) + cu] = v;
    }
}

// ---------------------------------------------------------------------------
// MFMA GEMM 1: qkv[m][n] (bf16, N=1536) = xb[m][k] * wqb[n][k]
// 128x128 tile, BK=64, 4 waves (2x2), 16x16x32 bf16 MFMA, fragment-order LDS.
// ---------------------------------------------------------------------------
__global__ __launch_bounds__(256)
void gemm_qkv(const u16* __restrict__ A, const u16* __restrict__ B,
              u16* __restrict__ C){
    __shared__ __align__(16) u16 As[8192];    // 16 tiles of 16x32 in frag order
    __shared__ __align__(16) u16 Bs[8192];
    const int t = threadIdx.x;
    const int w = t>>6, l = t&63, lr = l&15, lq = l>>4;
    const int wm = w&1, wn = w>>1;
    const int n0 = blockIdx.x*128;
    const int m0 = blockIdx.y*128;
    const u16* ag[4]; const u16* bg[4]; u16* al[4]; u16* bl[4];
    #pragma unroll
    for (int i=0;i<4;i++){
        int tt = w*4+i;                       // 0..15; tt = ks*8 + sub
        int ks = tt>>3, sub = tt&7;
        ag[i] = A + (size_t)(m0 + sub*16 + lr)*DIM + ks*32 + lq*8;
        bg[i] = B + (size_t)(n0 + sub*16 + lr)*DIM + ks*32 + lq*8;
        al[i] = &As[tt*512];
        bl[i] = &Bs[tt*512];
    }
    floatx4 acc[4][4] = {};
    for (int kt=0; kt<DIM; kt+=64){
        #pragma unroll
        for (int i=0;i<4;i++){ gload16(ag[i]+kt, al[i]); gload16(bg[i]+kt, bl[i]); }
        __syncthreads();
        #pragma unroll
        for (int ks=0;ks<2;ks++){
            short8 a[4], b[4];
            #pragma unroll
            for (int mi=0;mi<4;mi++) a[mi] = *(const short8*)&As[(ks*8 + wm*4 + mi)*512 + l*8];
            #pragma unroll
            for (int ni=0;ni<4;ni++) b[ni] = *(const short8*)&Bs[(ks*8 + wn*4 + ni)*512 + l*8];
            #pragma unroll
            for (int mi=0;mi<4;mi++)
                #pragma unroll
                for (int ni=0;ni<4;ni++)
                    acc[mi][ni] = __builtin_amdgcn_mfma_f32_16x16x32_bf16(a[mi], b[ni], acc[mi][ni], 0,0,0);
        }
        __syncthreads();
    }
    // epilogue: C/D layout col=lane&15 (n), row=quad*4+reg (m)
    #pragma unroll
    for (int mi=0;mi<4;mi++){
        #pragma unroll
        for (int r=0;r<4;r++){
            int m = m0 + wm*64 + mi*16 + lq*4 + r;
            u16* crow = C + (size_t)m*N_QKV + n0 + wn*64 + lr;
            #pragma unroll
            for (int ni=0;ni<4;ni++) crow[ni*16] = f2b(acc[mi][ni][r]);
        }
    }
}

// ---------------------------------------------------------------------------
// Kernel 2: width-axis attention (unchanged from round 2; bf16 in/out in ws)
// ---------------------------------------------------------------------------
__global__ __launch_bounds__(256)
void attn_kernel(const u16* __restrict__ qkv, u16* __restrict__ attno){
    __shared__ u32 Qs[96][33];      // Q, then V (reused)
    __shared__ u32 Ks[96][33];
    __shared__ float Ss[96][97];
    const int t   = threadIdx.x;
    const int blk = blockIdx.x;     // 3072
    const int row  = blk % HH;
    const int bh   = blk / HH;
    const int head = bh & 7;
    const int bat  = bh >> 3;
    const u32* qkv32 = (const u32*)qkv;
    const size_t pixrow = (size_t)(bat*NPIX + row*WW);
    const size_t base2  = pixrow*768 + (size_t)head*32;
    const int dd = t & 31;
    const int j0 = t >> 5;
    for (int j=j0;j<WW;j+=8){
        Qs[j][dd] = qkv32[base2 +       (size_t)j*768 + dd];
        Ks[j][dd] = qkv32[base2 + 256 + (size_t)j*768 + dd];
    }
    __syncthreads();
    const int tx = t & 15, ty = t >> 4;
    {   // S = scale * Q K^T
        float acc[6][6] = {{0.f}};
        for (int d2=0; d2<32; d2++){
            float ql[6], qh[6], kl[6], kh[6];
            #pragma unroll
            for (int a=0;a<6;a++){ u32 u = Qs[ty*6+a][d2]; ql[a]=blo(u); qh[a]=bhi(u); }
            #pragma unroll
            for (int c=0;c<6;c++){ u32 u = Ks[tx*6+c][d2]; kl[c]=blo(u); kh[c]=bhi(u); }
            #pragma unroll
            for (int a=0;a<6;a++)
                #pragma unroll
                for (int c=0;c<6;c++) acc[a][c] += ql[a]*kl[c] + qh[a]*kh[c];
        }
        #pragma unroll
        for (int a=0;a<6;a++)
            #pragma unroll
            for (int c=0;c<6;c++) Ss[ty*6+a][tx*6+c] = acc[a][c]*SCALE;
    }
    __syncthreads();
    for (int j=j0;j<WW;j+=8){
        Qs[j][dd] = qkv32[base2 + 512 + (size_t)j*768 + dd];  // V
    }
    if (t < HH){
        float m = -1e30f;
        for (int j=0;j<WW;j++) m = fmaxf(m, Ss[t][j]);
        float s = 0.f;
        for (int j=0;j<WW;j++){ float e = __expf(Ss[t][j]-m); Ss[t][j]=e; s+=e; }
        float r = 1.f/s;
        for (int j=0;j<WW;j++) Ss[t][j] *= r;
    }
    __syncthreads();
    {   // O = P V
        float acc[6][4] = {{0.f}};
        for (int j=0;j<WW;j++){
            u32 u0 = Qs[j][tx*2], u1 = Qs[j][tx*2+1];
            float v0=blo(u0), v1=bhi(u0), v2=blo(u1), v3=bhi(u1);
            #pragma unroll
            for (int a=0;a<6;a++){
                float p = Ss[ty*6+a][j];
                acc[a][0]+=p*v0; acc[a][1]+=p*v1; acc[a][2]+=p*v2; acc[a][3]+=p*v3;
            }
        }
        u32* o32 = (u32*)attno;
        #pragma unroll
        for (int a=0;a<6;a++){
            size_t pix = pixrow + (size_t)(ty*6 + a);
            size_t ob  = pix*256 + (size_t)head*32 + tx*2;
            o32[ob]   = pack2(acc[a][0], acc[a][1]);
            o32[ob+1] = pack2(acc[a][2], acc[a][3]);
        }
    }
}

// ---------------------------------------------------------------------------
// MFMA GEMM 2: out[b][n][pix] = attn_ws[m][k] * wob[n][k] + bias[n]
// Same core; LDS-staged transposed epilogue for coalesced [n][pix] stores.
// ---------------------------------------------------------------------------
__global__ __launch_bounds__(256)
void gemm_out(const u16* __restrict__ A, const u16* __restrict__ B,
              const void* __restrict__ bias, const int* __restrict__ flag,
              void* __restrict__ outv){
    __shared__ __align__(16) union ShMem {
        struct { u16 A[8192]; u16 B[8192]; } s;
        float ct[4][16][68];                  // per-wave [n][m] transpose buffer
    } sh;
    const int t = threadIdx.x;
    const int w = t>>6, l = t&63, lr = l&15, lq = l>>4;
    const int wm = w&1, wn = w>>1;
    const int n0 = blockIdx.x*128;
    const int m0 = blockIdx.y*128;
    const u16* ag[4]; const u16* bg[4]; u16* al[4]; u16* bl[4];
    #pragma unroll
    for (int i=0;i<4;i++){
        int tt = w*4+i;
        int ks = tt>>3, sub = tt&7;
        ag[i] = A + (size_t)(m0 + sub*16 + lr)*DIM + ks*32 + lq*8;
        bg[i] = B + (size_t)(n0 + sub*16 + lr)*DIM + ks*32 + lq*8;
        al[i] = &sh.s.A[tt*512];
        bl[i] = &sh.s.B[tt*512];
    }
    floatx4 acc[4][4] = {};
    for (int kt=0; kt<DIM; kt+=64){
        #pragma unroll
        for (int i=0;i<4;i++){ gload16(ag[i]+kt, al[i]); gload16(bg[i]+kt, bl[i]); }
        __syncthreads();
        #pragma unroll
        for (int ks=0;ks<2;ks++){
            short8 a[4], b[4];
            #pragma unroll
            for (int mi=0;mi<4;mi++) a[mi] = *(const short8*)&sh.s.A[(ks*8 + wm*4 + mi)*512 + l*8];
            #pragma unroll
            for (int ni=0;ni<4;ni++) b[ni] = *(const short8*)&sh.s.B[(ks*8 + wn*4 + ni)*512 + l*8];
            #pragma unroll
            for (int mi=0;mi<4;mi++)
                #pragma unroll
                for (int ni=0;ni<4;ni++)
                    acc[mi][ni] = __builtin_amdgcn_mfma_f32_16x16x32_bf16(a[mi], b[ni], acc[mi][ni], 0,0,0);
        }
        __syncthreads();
    }
    __syncthreads();            // K-loop LDS reads done before epilogue overwrite
    const int isb = *flag;
    const int bat  = m0 / NPIX;
    const int pix0 = m0 - bat*NPIX + wm*64;
    const u16*   b16 = (const u16*)bias;
    const float* b32 = (const float*)bias;
    for (int ni=0; ni<4; ni++){
        #pragma unroll
        for (int mi=0;mi<4;mi++)
            #pragma unroll
            for (int r=0;r<4;r++)
                sh.ct[w][lr][mi*16 + lq*4 + r] = acc[mi][ni][r];
        __syncthreads();
        #pragma unroll
        for (int p=0;p<4;p++){
            int nl = p*4 + lq;
            int ng = n0 + wn*64 + ni*16 + nl;
            float4 v = *(const float4*)&sh.ct[w][nl][lr*4];
            float bv = isb ? b2f(b16[ng]) : b32[ng];
            v.x+=bv; v.y+=bv; v.z+=bv; v.w+=bv;
            size_t off = ((size_t)(bat*DIM + ng))*NPIX + pix0 + lr*4;
            if (isb){
                u32* o32 = (u32*)outv;
                o32[off>>1]     = pack2(v.x, v.y);
                o32[(off>>1)+1] = pack2(v.z, v.w);
            } else {
                *(float4*)((float*)outv + off) = v;
            }
        }
        __syncthreads();
    }
}

extern "C" void kernel_launch(void* const* d_in, const int* in_sizes, int n_in,
                              void* d_out, int out_size, void* d_ws, size_t ws_size,
                              hipStream_t stream){
    const void* x    = d_in[0];
    const void* wqkv = d_in[1];
    const void* wout = d_in[2];
    const void* bout = d_in[3];
    char* wsb = (char*)d_ws;
    int* flag    = (int*)wsb;                                  // 256 B
    u16* xb      = (u16*)(wsb + 256);                          // [36864][512] bf16
    u16* attn_ws = xb;                                         // alias: xb dead after gemm1
    u16* wqb     = (u16*)(wsb + 256 + (size_t)M_TOT*DIM*2);    // [1536][512]
    u16* wob     = wqb + (size_t)N_QKV*DIM;                    // [512][512]
    u16* qkv_ws  = wob + (size_t)DIM*DIM;                      // [36864][1536]
    detect_dtype<<<1, 256, 0, stream>>>((const u16*)wqkv, flag);
    convert_w<<<4096, 256, 0, stream>>>(wqkv, wout, flag, wqb, wob);
    convert_x<<<dim3(144, 8, 4), 256, 0, stream>>>(x, flag, xb);
    gemm_qkv<<<dim3(12, 288), 256, 0, stream>>>(xb, wqb, qkv_ws);
    attn_kernel<<<3072, 256, 0, stream>>>(qkv_ws, attn_ws);
    gemm_out<<<dim3(4, 288), 256, 0, stream>>>(attn_ws, wob, bout, flag, d_out);
}

// Round 4
// 378.947 us; speedup vs baseline: 3.8348x; 1.2610x over previous
//
#include <hip/hip_runtime.h>

typedef unsigned short u16;
typedef unsigned int u32;
typedef __attribute__((ext_vector_type(8))) short short8;
typedef __attribute__((ext_vector_type(4))) float floatx4;

#define HEADS 8
#define DIM 512          // K for both GEMMs
#define HH 96
#define WW 96
#define NPIX 9216
#define M_TOT 36864
#define N_QKV 1536
#define SCALE 0.125f

__device__ __forceinline__ float b2f(u16 v){
    union{float f;u32 u;}x; x.u=((u32)v)<<16; return x.f;
}
__device__ __forceinline__ u16 f2b(float f){
    union{float f;u32 u;}x; x.f=f;
    u32 u=x.u + 0x7fffu + ((x.u>>16)&1u);
    return (u16)(u>>16);
}
__device__ __forceinline__ u32 pack2(float a,float b){
    return (u32)f2b(a) | ((u32)f2b(b)<<16);
}

// async global->LDS, 16 B per lane; lds dest = wave-uniform base + lane*16
__device__ __forceinline__ void gload16(const u16* g, u16* l){
    __builtin_amdgcn_global_load_lds(
        (const __attribute__((address_space(1))) u32*)g,
        (__attribute__((address_space(3))) u32*)l, 16, 0, 0);
}

// ---------------------------------------------------------------------------
// dtype detector (bf16 vs fp32 inputs)
// ---------------------------------------------------------------------------
__global__ void detect_dtype(const u16* __restrict__ wq, int* __restrict__ flag){
    __shared__ int cnt;
    if (threadIdx.x==0) cnt=0;
    __syncthreads();
    u16 u = wq[2*threadIdx.x];
    int e = (u>>7)&0xff;
    if (e>=100 && e<=128) atomicAdd(&cnt,1);
    __syncthreads();
    if (threadIdx.x==0) *flag = (cnt>128)?1:0;
}

// ---------------------------------------------------------------------------
// Weights -> bf16 (layout unchanged, [n][k] k-contiguous)
// ---------------------------------------------------------------------------
__global__ __launch_bounds__(256)
void convert_w(const void* __restrict__ wq, const void* __restrict__ wo,
               const int* __restrict__ flag, u16* __restrict__ wqb, u16* __restrict__ wob){
    const int isb = *flag;
    int i = blockIdx.x*256 + threadIdx.x;
    const int nq = N_QKV*DIM;                 // 786432
    if (i < nq){
        wqb[i] = isb ? ((const u16*)wq)[i] : f2b(((const float*)wq)[i]);
    } else {
        int j = i - nq;                       // < 262144
        wob[j] = isb ? ((const u16*)wo)[j] : f2b(((const float*)wo)[j]);
    }
}

// ---------------------------------------------------------------------------
// x [b][c][pix] (fp32 or bf16) -> xb [b*9216+pix][c] bf16   (transpose)
// ---------------------------------------------------------------------------
__global__ __launch_bounds__(256)
void convert_x(const void* __restrict__ xv, const int* __restrict__ flag,
               u16* __restrict__ xb){
    __shared__ u16 tile[64][65];
    const int isb = *flag;
    const int p0 = blockIdx.x*64, c0 = blockIdx.y*64, b = blockIdx.z;
    const int t = threadIdx.x;
    const int pl = t&63, c4 = t>>6;
    const float* x32 = (const float*)xv;
    const u16*   x16 = (const u16*)xv;
    size_t src = ((size_t)b*DIM + c0 + c4)*NPIX + p0 + pl;
    #pragma unroll
    for (int i=0;i<16;i++){
        int cl = c4 + i*4;
        size_t s = src + (size_t)i*4*NPIX;
        tile[cl][pl] = isb ? x16[s] : f2b(x32[s]);
    }
    __syncthreads();
    const int cu = t&31, r8 = t>>5;
    u32* xb32 = (u32*)xb;
    #pragma unroll
    for (int i=0;i<8;i++){
        int pr = r8 + i*8;
        u32 v = (u32)tile[2*cu][pr] | ((u32)tile[2*cu+1][pr]<<16);
        xb32[((size_t)b*NPIX + p0 + pr)*(DIM/2) + (c0>>1) + cu] = v;
    }
}

// ---------------------------------------------------------------------------
// MFMA GEMM 1: xb[m][k] * wqb[n][k].  n<1024 (Q,K) -> qk_ws[m][1024] bf16.
// n>=1024 (V) -> transposed into vt[(b*8+head)*64+d][pix] bf16 (for attn PV).
// 128x128 tile, BK=64, 4 waves (2x2), 16x16x32 bf16 MFMA, fragment-order LDS.
// ---------------------------------------------------------------------------
__global__ __launch_bounds__(256)
void gemm_qkv(const u16* __restrict__ A, const u16* __restrict__ B,
              u16* __restrict__ Cqk, u16* __restrict__ vt){
    __shared__ __align__(16) union ShMem {
        struct { u16 A[8192]; u16 B[8192]; } s;
        float ct[4][16][68];
    } sh;
    const int t = threadIdx.x;
    const int w = t>>6, l = t&63, lr = l&15, lq = l>>4;
    const int wm = w&1, wn = w>>1;
    const int n0 = blockIdx.x*128;
    const int m0 = blockIdx.y*128;
    const u16* ag[4]; const u16* bg[4]; u16* al[4]; u16* bl[4];
    #pragma unroll
    for (int i=0;i<4;i++){
        int tt = w*4+i;                       // tt = ks*8 + sub
        int ks = tt>>3, sub = tt&7;
        ag[i] = A + (size_t)(m0 + sub*16 + lr)*DIM + ks*32 + lq*8;
        bg[i] = B + (size_t)(n0 + sub*16 + lr)*DIM + ks*32 + lq*8;
        al[i] = &sh.s.A[tt*512];
        bl[i] = &sh.s.B[tt*512];
    }
    floatx4 acc[4][4] = {};
    for (int kt=0; kt<DIM; kt+=64){
        #pragma unroll
        for (int i=0;i<4;i++){ gload16(ag[i]+kt, al[i]); gload16(bg[i]+kt, bl[i]); }
        __syncthreads();
        #pragma unroll
        for (int ks=0;ks<2;ks++){
            short8 a[4], b[4];
            #pragma unroll
            for (int mi=0;mi<4;mi++) a[mi] = *(const short8*)&sh.s.A[(ks*8 + wm*4 + mi)*512 + l*8];
            #pragma unroll
            for (int ni=0;ni<4;ni++) b[ni] = *(const short8*)&sh.s.B[(ks*8 + wn*4 + ni)*512 + l*8];
            #pragma unroll
            for (int mi=0;mi<4;mi++)
                #pragma unroll
                for (int ni=0;ni<4;ni++)
                    acc[mi][ni] = __builtin_amdgcn_mfma_f32_16x16x32_bf16(a[mi], b[ni], acc[mi][ni], 0,0,0);
        }
        __syncthreads();
    }
    if (blockIdx.x < 8){
        // Q,K: normal epilogue into qk_ws rows of 1024
        #pragma unroll
        for (int mi=0;mi<4;mi++){
            #pragma unroll
            for (int r=0;r<4;r++){
                int m = m0 + wm*64 + mi*16 + lq*4 + r;
                u16* crow = Cqk + (size_t)m*1024 + n0 + wn*64 + lr;
                #pragma unroll
                for (int ni=0;ni<4;ni++) crow[ni*16] = f2b(acc[mi][ni][r]);
            }
        }
    } else {
        // V: transposed epilogue into vt[(bh*64+d)][pix]
        __syncthreads();
        const int bat  = m0 / NPIX;
        const int pixb = m0 - bat*NPIX + wm*64;
        for (int ni=0; ni<4; ni++){
            #pragma unroll
            for (int mi=0;mi<4;mi++)
                #pragma unroll
                for (int r=0;r<4;r++)
                    sh.ct[w][lr][mi*16 + lq*4 + r] = acc[mi][ni][r];
            __syncthreads();
            #pragma unroll
            for (int p=0;p<4;p++){
                int nl = p*4 + lq;
                int ch = n0 + wn*64 + ni*16 + nl - 1024;  // 0..511 = head*64+d
                int bh2 = bat*8 + (ch>>6);
                int dd  = ch & 63;
                float4 v = *(const float4*)&sh.ct[w][nl][lr*4];
                size_t off = ((size_t)(bh2*64+dd))*NPIX + pixb + lr*4;
                u32* o32 = (u32*)vt;
                o32[off>>1]     = pack2(v.x, v.y);
                o32[(off>>1)+1] = pack2(v.z, v.w);
            }
            __syncthreads();
        }
    }
}

// ---------------------------------------------------------------------------
// Kernel 2: width-axis MFMA attention. One block per (b, head, row), 4 waves.
// qk_ws [pix][1024] (Q ch 0..511, K ch 512..1023), vt [(bh*64+d)][pix].
// QK^T (MFMA) -> Ss fp32 [96][97] -> softmax (unnormalized exp, rinv saved)
// -> PV (MFMA, P frags built from Ss) -> O scaled by rinv -> attno [pix][512].
// ---------------------------------------------------------------------------
__global__ __launch_bounds__(256)
void attn_kernel(const u16* __restrict__ qk, const u16* __restrict__ vt,
                 u16* __restrict__ attno){
    __shared__ __align__(16) u16 Qf[6144];   // Q frag tiles; later V^T tiles
    __shared__ __align__(16) u16 Kf[6144];   // K frag tiles
    __shared__ float Ss[96][97];
    __shared__ float smax[96][2], ssum[96][2], rinv[96];
    const int t = threadIdx.x;
    const int w = t>>6, l = t&63, lr = l&15, lq = l>>4;
    const int wm = w&1, wn = w>>1;
    const int blk = blockIdx.x;              // 3072
    const int row  = blk % HH;
    const int bh   = blk / HH;               // bat*8 + head
    const int head = bh & 7;
    const int bat  = bh >> 3;
    const size_t pixrow = (size_t)bat*NPIX + row*WW;
    const u16* qbase = qk + pixrow*1024 + head*64;
    // stage Q (tiles 0..11) and K (tiles 12..23); 6 tiles per wave
    #pragma unroll
    for (int i=0;i<6;i++){
        int c  = w*6 + i;
        int c2 = (c<12) ? c : (c-12);
        int mt = c2>>1, ks = c2&1;
        const u16* g = qbase + (size_t)(mt*16+lr)*1024 + ks*32 + lq*8 + ((c<12)?0:512);
        u16* dst = ((c<12)?Qf:Kf) + c2*512 + l*8;
        gload16(g, dst);
    }
    __syncthreads();
    // QK^T: wave (wm,wn) covers m-tiles wm*3.., n-tiles wn*3..
    {
        floatx4 acc[3][3] = {};
        #pragma unroll
        for (int ks=0;ks<2;ks++){
            short8 af[3], bf[3];
            #pragma unroll
            for (int i=0;i<3;i++) af[i] = *(const short8*)&Qf[((wm*3+i)*2+ks)*512 + l*8];
            #pragma unroll
            for (int j=0;j<3;j++) bf[j] = *(const short8*)&Kf[((wn*3+j)*2+ks)*512 + l*8];
            #pragma unroll
            for (int i=0;i<3;i++)
                #pragma unroll
                for (int j=0;j<3;j++)
                    acc[i][j] = __builtin_amdgcn_mfma_f32_16x16x32_bf16(af[i], bf[j], acc[i][j], 0,0,0);
        }
        #pragma unroll
        for (int i=0;i<3;i++)
            #pragma unroll
            for (int j=0;j<3;j++)
                #pragma unroll
                for (int r=0;r<4;r++)
                    Ss[(wm*3+i)*16 + lq*4 + r][(wn*3+j)*16 + lr] = acc[i][j][r]*SCALE;
    }
    __syncthreads();
    // stage V^T into Qf (dead): wave w = d-tile, i = k(j)-tile
    #pragma unroll
    for (int i=0;i<3;i++){
        const u16* g = vt + (size_t)(bh*64 + w*16 + lr)*NPIX + row*WW + i*32 + lq*8;
        gload16(g, Qf + (w*3+i)*512 + l*8);
    }
    // softmax: 2 threads per row, 48 cols each; exp left unnormalized
    const int srow = t>>1, shalf = t&1;
    if (t < 192){
        float m = -1e30f;
        #pragma unroll 8
        for (int j=0;j<48;j++) m = fmaxf(m, Ss[srow][shalf*48+j]);
        smax[srow][shalf] = m;
    }
    __syncthreads();   // also drains V^T staging
    if (t < 192){
        float m2 = fmaxf(smax[srow][0], smax[srow][1]);
        float s = 0.f;
        #pragma unroll 8
        for (int j=0;j<48;j++){
            float e = __expf(Ss[srow][shalf*48+j] - m2);
            Ss[srow][shalf*48+j] = e; s += e;
        }
        ssum[srow][shalf] = s;
    }
    __syncthreads();
    if (t < 192 && shalf==0) rinv[srow] = 1.f/(ssum[srow][0]+ssum[srow][1]);
    // PV: wave (wm,wn): m-tiles wm*3.., d-tiles wn*2..
    floatx4 o[3][2] = {};
    for (int ks2=0;ks2<3;ks2++){
        short8 bf2[2];
        #pragma unroll
        for (int bb=0;bb<2;bb++)
            bf2[bb] = *(const short8*)&Qf[((wn*2+bb)*3+ks2)*512 + l*8];
        #pragma unroll
        for (int aa=0;aa<3;aa++){
            int m = (wm*3+aa)*16 + lr;
            union { short8 s; u32 u[4]; } a;
            const float* srcp = &Ss[m][ks2*32 + lq*8];
            #pragma unroll
            for (int p=0;p<4;p++) a.u[p] = pack2(srcp[2*p], srcp[2*p+1]);
            #pragma unroll
            for (int bb=0;bb<2;bb++)
                o[aa][bb] = __builtin_amdgcn_mfma_f32_16x16x32_bf16(a.s, bf2[bb], o[aa][bb], 0,0,0);
        }
    }
    __syncthreads();   // rinv visible to all
    // epilogue: O[i][d] = acc*rinv[i] -> attno[(pixrow+i)*512 + head*64 + d]
    #pragma unroll
    for (int aa=0;aa<3;aa++){
        #pragma unroll
        for (int r=0;r<4;r++){
            int i = (wm*3+aa)*16 + lq*4 + r;
            float rv = rinv[i];
            u16* orow = attno + (pixrow + i)*512 + head*64 + wn*32 + lr;
            orow[0]  = f2b(o[aa][0][r]*rv);
            orow[16] = f2b(o[aa][1][r]*rv);
        }
    }
}

// ---------------------------------------------------------------------------
// MFMA GEMM 2: out[b][n][pix] = attn_ws[m][k] * wob[n][k] + bias[n]
// ---------------------------------------------------------------------------
__global__ __launch_bounds__(256)
void gemm_out(const u16* __restrict__ A, const u16* __restrict__ B,
              const void* __restrict__ bias, const int* __restrict__ flag,
              void* __restrict__ outv){
    __shared__ __align__(16) union ShMem {
        struct { u16 A[8192]; u16 B[8192]; } s;
        float ct[4][16][68];
    } sh;
    const int t = threadIdx.x;
    const int w = t>>6, l = t&63, lr = l&15, lq = l>>4;
    const int wm = w&1, wn = w>>1;
    const int n0 = blockIdx.x*128;
    const int m0 = blockIdx.y*128;
    const u16* ag[4]; const u16* bg[4]; u16* al[4]; u16* bl[4];
    #pragma unroll
    for (int i=0;i<4;i++){
        int tt = w*4+i;
        int ks = tt>>3, sub = tt&7;
        ag[i] = A + (size_t)(m0 + sub*16 + lr)*DIM + ks*32 + lq*8;
        bg[i] = B + (size_t)(n0 + sub*16 + lr)*DIM + ks*32 + lq*8;
        al[i] = &sh.s.A[tt*512];
        bl[i] = &sh.s.B[tt*512];
    }
    floatx4 acc[4][4] = {};
    for (int kt=0; kt<DIM; kt+=64){
        #pragma unroll
        for (int i=0;i<4;i++){ gload16(ag[i]+kt, al[i]); gload16(bg[i]+kt, bl[i]); }
        __syncthreads();
        #pragma unroll
        for (int ks=0;ks<2;ks++){
            short8 a[4], b[4];
            #pragma unroll
            for (int mi=0;mi<4;mi++) a[mi] = *(const short8*)&sh.s.A[(ks*8 + wm*4 + mi)*512 + l*8];
            #pragma unroll
            for (int ni=0;ni<4;ni++) b[ni] = *(const short8*)&sh.s.B[(ks*8 + wn*4 + ni)*512 + l*8];
            #pragma unroll
            for (int mi=0;mi<4;mi++)
                #pragma unroll
                for (int ni=0;ni<4;ni++)
                    acc[mi][ni] = __builtin_amdgcn_mfma_f32_16x16x32_bf16(a[mi], b[ni], acc[mi][ni], 0,0,0);
        }
        __syncthreads();
    }
    __syncthreads();
    const int isb = *flag;
    const int bat  = m0 / NPIX;
    const int pix0 = m0 - bat*NPIX + wm*64;
    const u16*   b16 = (const u16*)bias;
    const float* b32 = (const float*)bias;
    for (int ni=0; ni<4; ni++){
        #pragma unroll
        for (int mi=0;mi<4;mi++)
            #pragma unroll
            for (int r=0;r<4;r++)
                sh.ct[w][lr][mi*16 + lq*4 + r] = acc[mi][ni][r];
        __syncthreads();
        #pragma unroll
        for (int p=0;p<4;p++){
            int nl = p*4 + lq;
            int ng = n0 + wn*64 + ni*16 + nl;
            float4 v = *(const float4*)&sh.ct[w][nl][lr*4];
            float bv = isb ? b2f(b16[ng]) : b32[ng];
            v.x+=bv; v.y+=bv; v.z+=bv; v.w+=bv;
            size_t off = ((size_t)(bat*DIM + ng))*NPIX + pix0 + lr*4;
            if (isb){
                u32* o32 = (u32*)outv;
                o32[off>>1]     = pack2(v.x, v.y);
                o32[(off>>1)+1] = pack2(v.z, v.w);
            } else {
                *(float4*)((float*)outv + off) = v;
            }
        }
        __syncthreads();
    }
}

extern "C" void kernel_launch(void* const* d_in, const int* in_sizes, int n_in,
                              void* d_out, int out_size, void* d_ws, size_t ws_size,
                              hipStream_t stream){
    const void* x    = d_in[0];
    const void* wqkv = d_in[1];
    const void* wout = d_in[2];
    const void* bout = d_in[3];
    char* wsb = (char*)d_ws;
    int* flag    = (int*)wsb;                                  // 256 B
    u16* xb      = (u16*)(wsb + 256);                          // [36864][512] bf16
    u16* attn_ws = xb;                                         // alias: xb dead after gemm1
    u16* wqb     = xb + (size_t)M_TOT*DIM;                     // [1536][512]
    u16* wob     = wqb + (size_t)N_QKV*DIM;                    // [512][512]
    u16* qk_ws   = wob + (size_t)DIM*DIM;                      // [36864][1024] (Q,K)
    u16* vt_ws   = qk_ws + (size_t)M_TOT*1024;                 // [32*64][9216] (V^T)
    detect_dtype<<<1, 256, 0, stream>>>((const u16*)wqkv, flag);
    convert_w<<<4096, 256, 0, stream>>>(wqkv, wout, flag, wqb, wob);
    convert_x<<<dim3(144, 8, 4), 256, 0, stream>>>(x, flag, xb);
    gemm_qkv<<<dim3(12, 288), 256, 0, stream>>>(xb, wqb, qk_ws, vt_ws);
    attn_kernel<<<3072, 256, 0, stream>>>(qk_ws, vt_ws, attn_ws);
    gemm_out<<<dim3(4, 288), 256, 0, stream>>>(attn_ws, wob, bout, flag, d_out);
}

// Round 5
// 370.876 us; speedup vs baseline: 3.9183x; 1.0218x over previous
//
#include <hip/hip_runtime.h>

typedef unsigned short u16;
typedef unsigned int u32;
typedef __attribute__((ext_vector_type(8))) short short8;
typedef __attribute__((ext_vector_type(4))) float floatx4;

#define HEADS 8
#define DIM 512          // K for both GEMMs
#define HH 96
#define WW 96
#define NPIX 9216
#define M_TOT 36864
#define N_QKV 1536
#define SCALE 0.125f

__device__ __forceinline__ float b2f(u16 v){
    union{float f;u32 u;}x; x.u=((u32)v)<<16; return x.f;
}
__device__ __forceinline__ u16 f2b(float f){
    union{float f;u32 u;}x; x.f=f;
    u32 u=x.u + 0x7fffu + ((x.u>>16)&1u);
    return (u16)(u>>16);
}
__device__ __forceinline__ u32 pack2(float a,float b){
    return (u32)f2b(a) | ((u32)f2b(b)<<16);
}

// async global->LDS, 16 B per lane; lds dest = wave-uniform base + lane*16
__device__ __forceinline__ void gload16(const u16* g, u16* l){
    __builtin_amdgcn_global_load_lds(
        (const __attribute__((address_space(1))) u32*)g,
        (__attribute__((address_space(3))) u32*)l, 16, 0, 0);
}

// ---------------------------------------------------------------------------
// dtype detector (bf16 vs fp32 inputs)
// ---------------------------------------------------------------------------
__global__ void detect_dtype(const u16* __restrict__ wq, int* __restrict__ flag){
    __shared__ int cnt;
    if (threadIdx.x==0) cnt=0;
    __syncthreads();
    u16 u = wq[2*threadIdx.x];
    int e = (u>>7)&0xff;
    if (e>=100 && e<=128) atomicAdd(&cnt,1);
    __syncthreads();
    if (threadIdx.x==0) *flag = (cnt>128)?1:0;
}

// ---------------------------------------------------------------------------
// Weights -> bf16 (layout unchanged, [n][k] k-contiguous)
// ---------------------------------------------------------------------------
__global__ __launch_bounds__(256)
void convert_w(const void* __restrict__ wq, const void* __restrict__ wo,
               const int* __restrict__ flag, u16* __restrict__ wqb, u16* __restrict__ wob){
    const int isb = *flag;
    int i = blockIdx.x*256 + threadIdx.x;
    const int nq = N_QKV*DIM;                 // 786432
    if (i < nq){
        wqb[i] = isb ? ((const u16*)wq)[i] : f2b(((const float*)wq)[i]);
    } else {
        int j = i - nq;                       // < 262144
        wob[j] = isb ? ((const u16*)wo)[j] : f2b(((const float*)wo)[j]);
    }
}

// ---------------------------------------------------------------------------
// x [b][c][pix] (fp32 or bf16) -> xb [b*9216+pix][c] bf16   (transpose)
// ---------------------------------------------------------------------------
__global__ __launch_bounds__(256)
void convert_x(const void* __restrict__ xv, const int* __restrict__ flag,
               u16* __restrict__ xb){
    __shared__ u16 tile[64][65];
    const int isb = *flag;
    const int p0 = blockIdx.x*64, c0 = blockIdx.y*64, b = blockIdx.z;
    const int t = threadIdx.x;
    const int pl = t&63, c4 = t>>6;
    const float* x32 = (const float*)xv;
    const u16*   x16 = (const u16*)xv;
    size_t src = ((size_t)b*DIM + c0 + c4)*NPIX + p0 + pl;
    #pragma unroll
    for (int i=0;i<16;i++){
        int cl = c4 + i*4;
        size_t s = src + (size_t)i*4*NPIX;
        tile[cl][pl] = isb ? x16[s] : f2b(x32[s]);
    }
    __syncthreads();
    const int cu = t&31, r8 = t>>5;
    u32* xb32 = (u32*)xb;
    #pragma unroll
    for (int i=0;i<8;i++){
        int pr = r8 + i*8;
        u32 v = (u32)tile[2*cu][pr] | ((u32)tile[2*cu+1][pr]<<16);
        xb32[((size_t)b*NPIX + p0 + pr)*(DIM/2) + (c0>>1) + cu] = v;
    }
}

// ---------------------------------------------------------------------------
// MFMA GEMM 1: xb[m][k] * wqb[n][k].  bx<8 (Q,K) -> qk_ws[m][1024] bf16.
// bx>=8 (V) -> transposed into vt[(b*8+head)*64+d][pix] bf16 (for attn PV).
// 1D grid 3456 + XCD swizzle: blocks sharing an A-tile land on one XCD.
// Vectorized LDS-transpose epilogues (dwordx4 stores).
// ---------------------------------------------------------------------------
__global__ __launch_bounds__(256)
void gemm_qkv(const u16* __restrict__ A, const u16* __restrict__ B,
              u16* __restrict__ Cqk, u16* __restrict__ vt){
    __shared__ __align__(16) union ShMem {
        struct { u16 A[8192]; u16 B[8192]; } s;
        float ct[4][16][68];                  // per-wave transpose buffer
    } sh;
    const int id = blockIdx.x;
    const int xcd = id & 7, slot = id >> 3;   // 8 XCDs round-robin by id
    const int by = xcd*36 + slot/12;          // same A-tile -> same XCD
    const int bx = slot - (slot/12)*12;
    const int t = threadIdx.x;
    const int w = t>>6, l = t&63, lr = l&15, lq = l>>4;
    const int wm = w&1, wn = w>>1;
    const int n0 = bx*128;
    const int m0 = by*128;
    const u16* ag[4]; const u16* bg[4]; u16* al[4]; u16* bl[4];
    #pragma unroll
    for (int i=0;i<4;i++){
        int tt = w*4+i;                       // tt = ks*8 + sub
        int ks = tt>>3, sub = tt&7;
        ag[i] = A + (size_t)(m0 + sub*16 + lr)*DIM + ks*32 + lq*8;
        bg[i] = B + (size_t)(n0 + sub*16 + lr)*DIM + ks*32 + lq*8;
        al[i] = &sh.s.A[tt*512];
        bl[i] = &sh.s.B[tt*512];
    }
    floatx4 acc[4][4] = {};
    for (int kt=0; kt<DIM; kt+=64){
        #pragma unroll
        for (int i=0;i<4;i++){ gload16(ag[i]+kt, al[i]); gload16(bg[i]+kt, bl[i]); }
        __syncthreads();
        #pragma unroll
        for (int ks=0;ks<2;ks++){
            short8 a[4], b[4];
            #pragma unroll
            for (int mi=0;mi<4;mi++) a[mi] = *(const short8*)&sh.s.A[(ks*8 + wm*4 + mi)*512 + l*8];
            #pragma unroll
            for (int ni=0;ni<4;ni++) b[ni] = *(const short8*)&sh.s.B[(ks*8 + wn*4 + ni)*512 + l*8];
            #pragma unroll
            for (int mi=0;mi<4;mi++)
                #pragma unroll
                for (int ni=0;ni<4;ni++)
                    acc[mi][ni] = __builtin_amdgcn_mfma_f32_16x16x32_bf16(a[mi], b[ni], acc[mi][ni], 0,0,0);
        }
        __syncthreads();
    }
    if (bx < 8){
        // Q,K epilogue: per-wave LDS transpose -> 2x dwordx4 store per pass
        #pragma unroll
        for (int mi=0;mi<4;mi++){
            #pragma unroll
            for (int ni=0;ni<4;ni++)
                #pragma unroll
                for (int r=0;r<4;r++)
                    sh.ct[w][lq*4+r][ni*16+lr] = acc[mi][ni][r];
            // per-wave buffer: DS in-order within wave, no barrier needed
            int row = l>>2, cg = l&3;
            const float* cp = &sh.ct[w][row][cg*16];
            float4 v0 = *(const float4*)(cp);
            float4 v1 = *(const float4*)(cp+4);
            float4 v2 = *(const float4*)(cp+8);
            float4 v3 = *(const float4*)(cp+12);
            uint4 s0, s1;
            s0.x=pack2(v0.x,v0.y); s0.y=pack2(v0.z,v0.w);
            s0.z=pack2(v1.x,v1.y); s0.w=pack2(v1.z,v1.w);
            s1.x=pack2(v2.x,v2.y); s1.y=pack2(v2.z,v2.w);
            s1.z=pack2(v3.x,v3.y); s1.w=pack2(v3.z,v3.w);
            u16* dst = Cqk + (size_t)(m0+wm*64+mi*16+row)*1024 + n0 + wn*64 + cg*16;
            *((uint4*)dst)     = s0;
            *((uint4*)(dst+8)) = s1;
        }
    } else {
        // V epilogue: transposed into vt[(bh*64+d)][pix], dwordx4 stores
        const int bat  = m0 / NPIX;
        const int pixb = m0 - bat*NPIX + wm*64;
        for (int ni=0; ni<4; ni++){
            #pragma unroll
            for (int mi=0;mi<4;mi++)
                #pragma unroll
                for (int r=0;r<4;r++)
                    sh.ct[w][lr][mi*16 + lq*4 + r] = acc[mi][ni][r];
            #pragma unroll
            for (int p=0;p<2;p++){
                int nl = (l>>3) + p*8;
                int ch = n0 + wn*64 + ni*16 + nl - 1024;  // head*64+d
                int bh2 = bat*8 + (ch>>6);
                int dd  = ch & 63;
                const float* cp = &sh.ct[w][nl][(l&7)*8];
                float4 v0 = *(const float4*)cp;
                float4 v1 = *(const float4*)(cp+4);
                uint4 s;
                s.x=pack2(v0.x,v0.y); s.y=pack2(v0.z,v0.w);
                s.z=pack2(v1.x,v1.y); s.w=pack2(v1.z,v1.w);
                *(uint4*)(vt + (size_t)(bh2*64+dd)*NPIX + pixb + (l&7)*8) = s;
            }
        }
    }
}

// ---------------------------------------------------------------------------
// Kernel 2: width-axis MFMA attention. One block per (b, head, row), 4 waves.
// QK^T (MFMA) -> Ss fp32 -> softmax writes P as bf16 into dead K region
// -> PV (MFMA, direct short8 A-frags) -> O via LDS restage, dwordx4 stores.
// ---------------------------------------------------------------------------
__global__ __launch_bounds__(256)
void attn_kernel(const u16* __restrict__ qk, const u16* __restrict__ vt,
                 u16* __restrict__ attno){
    __shared__ __align__(16) u16 Qf[6144];   // Q frag tiles; later V^T tiles
    __shared__ __align__(16) u16 Pb[9984];   // K frag tiles (6144); later P bf16 [96][104]; later O [96][72]
    __shared__ float Ss[96][97];
    __shared__ float smax[96][2], ssum[96][2], rinv[96];
    const int t = threadIdx.x;
    const int w = t>>6, l = t&63, lr = l&15, lq = l>>4;
    const int wm = w&1, wn = w>>1;
    const int blk = blockIdx.x;              // 3072
    const int row  = blk % HH;
    const int bh   = blk / HH;               // bat*8 + head
    const int head = bh & 7;
    const int bat  = bh >> 3;
    const size_t pixrow = (size_t)bat*NPIX + row*WW;
    const u16* qbase = qk + pixrow*1024 + head*64;
    // stage Q (tiles 0..11 -> Qf) and K (tiles 0..11 -> Pb); 6 per wave
    #pragma unroll
    for (int i=0;i<6;i++){
        int c  = w*6 + i;
        int c2 = (c<12) ? c : (c-12);
        int mt = c2>>1, ks = c2&1;
        const u16* g = qbase + (size_t)(mt*16+lr)*1024 + ks*32 + lq*8 + ((c<12)?0:512);
        u16* dst = ((c<12)?Qf:Pb) + c2*512 + l*8;
        gload16(g, dst);
    }
    __syncthreads();
    // QK^T: wave (wm,wn) covers m-tiles wm*3.., n-tiles wn*3..
    {
        floatx4 acc[3][3] = {};
        #pragma unroll
        for (int ks=0;ks<2;ks++){
            short8 af[3], bf[3];
            #pragma unroll
            for (int i=0;i<3;i++) af[i] = *(const short8*)&Qf[((wm*3+i)*2+ks)*512 + l*8];
            #pragma unroll
            for (int j=0;j<3;j++) bf[j] = *(const short8*)&Pb[((wn*3+j)*2+ks)*512 + l*8];
            #pragma unroll
            for (int i=0;i<3;i++)
                #pragma unroll
                for (int j=0;j<3;j++)
                    acc[i][j] = __builtin_amdgcn_mfma_f32_16x16x32_bf16(af[i], bf[j], acc[i][j], 0,0,0);
        }
        #pragma unroll
        for (int i=0;i<3;i++)
            #pragma unroll
            for (int j=0;j<3;j++)
                #pragma unroll
                for (int r=0;r<4;r++)
                    Ss[(wm*3+i)*16 + lq*4 + r][(wn*3+j)*16 + lr] = acc[i][j][r]*SCALE;
    }
    __syncthreads();
    // stage V^T into Qf (dead): wave w = d-tile, i = k(j)-tile
    #pragma unroll
    for (int i=0;i<3;i++){
        const u16* g = vt + (size_t)(bh*64 + w*16 + lr)*NPIX + row*WW + i*32 + lq*8;
        gload16(g, Qf + (w*3+i)*512 + l*8);
    }
    // softmax: 2 threads per row, 48 cols each; P -> bf16 in Pb (K dead)
    const int srow = t>>1, shalf = t&1, sbase = shalf*48;
    if (t < 192){
        float m = -1e30f;
        #pragma unroll 8
        for (int j=0;j<48;j++) m = fmaxf(m, Ss[srow][sbase+j]);
        smax[srow][shalf] = m;
    }
    __syncthreads();   // smax ready; also drains V^T staging (vmcnt)
    if (t < 192){
        float m2 = fmaxf(smax[srow][0], smax[srow][1]);
        float s = 0.f;
        u32* prow = (u32*)&Pb[srow*104 + sbase];
        #pragma unroll 8
        for (int j=0;j<48;j+=2){
            float e0 = __expf(Ss[srow][sbase+j]   - m2);
            float e1 = __expf(Ss[srow][sbase+j+1] - m2);
            prow[j>>1] = pack2(e0, e1);
            s += e0 + e1;
        }
        ssum[srow][shalf] = s;
    }
    __syncthreads();
    if (t < 192 && shalf==0) rinv[srow] = 1.f/(ssum[srow][0]+ssum[srow][1]);
    // PV: wave (wm,wn): m-tiles wm*3.., d-tiles wn*2..; A-frags direct from Pb
    floatx4 o[3][2] = {};
    #pragma unroll
    for (int ks2=0;ks2<3;ks2++){
        short8 bf2[2];
        #pragma unroll
        for (int bb=0;bb<2;bb++)
            bf2[bb] = *(const short8*)&Qf[((wn*2+bb)*3+ks2)*512 + l*8];
        #pragma unroll
        for (int aa=0;aa<3;aa++){
            short8 af = *(const short8*)&Pb[((wm*3+aa)*16+lr)*104 + ks2*32 + lq*8];
            #pragma unroll
            for (int bb=0;bb<2;bb++)
                o[aa][bb] = __builtin_amdgcn_mfma_f32_16x16x32_bf16(af, bf2[bb], o[aa][bb], 0,0,0);
        }
    }
    __syncthreads();   // PV reads of Pb done; rinv visible
    // epilogue: O*rinv -> Pb as [96][72] bf16, then coalesced dwordx4 stores
    #pragma unroll
    for (int aa=0;aa<3;aa++){
        #pragma unroll
        for (int r=0;r<4;r++){
            int m = (wm*3+aa)*16 + lq*4 + r;
            float rv = rinv[m];
            int d0 = wn*32 + lr;
            Pb[m*72 + d0]      = f2b(o[aa][0][r]*rv);
            Pb[m*72 + d0 + 16] = f2b(o[aa][1][r]*rv);
        }
    }
    __syncthreads();
    #pragma unroll
    for (int i=0;i<3;i++){
        int idx = i*256 + t;                 // 768 = 96 rows x 8 segs
        int rr = idx>>3, seg = idx&7;
        uint4 vv = *(const uint4*)&Pb[rr*72 + seg*8];
        *(uint4*)(attno + (pixrow+rr)*512 + head*64 + seg*8) = vv;
    }
}

// ---------------------------------------------------------------------------
// MFMA GEMM 2: out[b][n][pix] = attn_ws[m][k] * wob[n][k] + bias[n]
// XCD swizzle; vectorized transposed epilogue.
// ---------------------------------------------------------------------------
__global__ __launch_bounds__(256)
void gemm_out(const u16* __restrict__ A, const u16* __restrict__ B,
              const void* __restrict__ bias, const int* __restrict__ flag,
              void* __restrict__ outv){
    __shared__ __align__(16) union ShMem {
        struct { u16 A[8192]; u16 B[8192]; } s;
        float ct[4][16][68];
    } sh;
    const int id = blockIdx.x;
    const int xcd = id & 7, slot = id >> 3;   // 1152 blocks
    const int by = xcd*36 + (slot>>2);
    const int bx = slot & 3;
    const int t = threadIdx.x;
    const int w = t>>6, l = t&63, lr = l&15, lq = l>>4;
    const int wm = w&1, wn = w>>1;
    const int n0 = bx*128;
    const int m0 = by*128;
    const u16* ag[4]; const u16* bg[4]; u16* al[4]; u16* bl[4];
    #pragma unroll
    for (int i=0;i<4;i++){
        int tt = w*4+i;
        int ks = tt>>3, sub = tt&7;
        ag[i] = A + (size_t)(m0 + sub*16 + lr)*DIM + ks*32 + lq*8;
        bg[i] = B + (size_t)(n0 + sub*16 + lr)*DIM + ks*32 + lq*8;
        al[i] = &sh.s.A[tt*512];
        bl[i] = &sh.s.B[tt*512];
    }
    floatx4 acc[4][4] = {};
    for (int kt=0; kt<DIM; kt+=64){
        #pragma unroll
        for (int i=0;i<4;i++){ gload16(ag[i]+kt, al[i]); gload16(bg[i]+kt, bl[i]); }
        __syncthreads();
        #pragma unroll
        for (int ks=0;ks<2;ks++){
            short8 a[4], b[4];
            #pragma unroll
            for (int mi=0;mi<4;mi++) a[mi] = *(const short8*)&sh.s.A[(ks*8 + wm*4 + mi)*512 + l*8];
            #pragma unroll
            for (int ni=0;ni<4;ni++) b[ni] = *(const short8*)&sh.s.B[(ks*8 + wn*4 + ni)*512 + l*8];
            #pragma unroll
            for (int mi=0;mi<4;mi++)
                #pragma unroll
                for (int ni=0;ni<4;ni++)
                    acc[mi][ni] = __builtin_amdgcn_mfma_f32_16x16x32_bf16(a[mi], b[ni], acc[mi][ni], 0,0,0);
        }
        __syncthreads();
    }
    const int isb = *flag;
    const int bat  = m0 / NPIX;
    const int pix0 = m0 - bat*NPIX + wm*64;
    const u16*   b16 = (const u16*)bias;
    const float* b32 = (const float*)bias;
    for (int ni=0; ni<4; ni++){
        #pragma unroll
        for (int mi=0;mi<4;mi++)
            #pragma unroll
            for (int r=0;r<4;r++)
                sh.ct[w][lr][mi*16 + lq*4 + r] = acc[mi][ni][r];
        #pragma unroll
        for (int p=0;p<2;p++){
            int nl = (l>>3) + p*8;
            int ng = n0 + wn*64 + ni*16 + nl;
            float bv = isb ? b2f(b16[ng]) : b32[ng];
            const float* cp = &sh.ct[w][nl][(l&7)*8];
            float4 v0 = *(const float4*)cp;
            float4 v1 = *(const float4*)(cp+4);
            v0.x+=bv; v0.y+=bv; v0.z+=bv; v0.w+=bv;
            v1.x+=bv; v1.y+=bv; v1.z+=bv; v1.w+=bv;
            size_t off = ((size_t)(bat*DIM + ng))*NPIX + pix0 + (l&7)*8;
            if (isb){
                uint4 s;
                s.x=pack2(v0.x,v0.y); s.y=pack2(v0.z,v0.w);
                s.z=pack2(v1.x,v1.y); s.w=pack2(v1.z,v1.w);
                *(uint4*)((u16*)outv + off) = s;
            } else {
                float* of = (float*)outv + off;
                *(float4*)of     = v0;
                *(float4*)(of+4) = v1;
            }
        }
    }
}

extern "C" void kernel_launch(void* const* d_in, const int* in_sizes, int n_in,
                              void* d_out, int out_size, void* d_ws, size_t ws_size,
                              hipStream_t stream){
    const void* x    = d_in[0];
    const void* wqkv = d_in[1];
    const void* wout = d_in[2];
    const void* bout = d_in[3];
    char* wsb = (char*)d_ws;
    int* flag    = (int*)wsb;                                  // 256 B
    u16* xb      = (u16*)(wsb + 256);                          // [36864][512] bf16
    u16* attn_ws = xb;                                         // alias: xb dead after gemm1
    u16* wqb     = xb + (size_t)M_TOT*DIM;                     // [1536][512]
    u16* wob     = wqb + (size_t)N_QKV*DIM;                    // [512][512]
    u16* qk_ws   = wob + (size_t)DIM*DIM;                      // [36864][1024] (Q,K)
    u16* vt_ws   = qk_ws + (size_t)M_TOT*1024;                 // [32*64][9216] (V^T)
    detect_dtype<<<1, 256, 0, stream>>>((const u16*)wqkv, flag);
    convert_w<<<4096, 256, 0, stream>>>(wqkv, wout, flag, wqb, wob);
    convert_x<<<dim3(144, 8, 4), 256, 0, stream>>>(x, flag, xb);
    gemm_qkv<<<3456, 256, 0, stream>>>(xb, wqb, qk_ws, vt_ws);
    attn_kernel<<<3072, 256, 0, stream>>>(qk_ws, vt_ws, attn_ws);
    gemm_out<<<1152, 256, 0, stream>>>(attn_ws, wob, bout, flag, d_out);
}